// Round 8
// baseline (198.388 us; speedup 1.0000x reference)
//
#include <hip/hip_runtime.h>
#include <hip/hip_bf16.h>

#define ALPHA   0.1f
#define S_DECAY 0.95f
#define P_DECAY 0.99f
#define D_EMB   768
#define DK      256

// ---- DPP wave-64 reduction helpers (validated rounds 1-7) ----
template<int ctrl, int row_mask>
__device__ __forceinline__ float dpp_add(float x) {
    int y = __builtin_amdgcn_update_dpp(0, __float_as_int(x), ctrl, row_mask, 0xF, true);
    return x + __int_as_float(y);
}

template<int N>
__device__ __forceinline__ void wave_allred_arr(float (&x)[N]) {
#pragma unroll
    for (int n = 0; n < N; ++n) x[n] = dpp_add<0xB1,  0xF>(x[n]);
#pragma unroll
    for (int n = 0; n < N; ++n) x[n] = dpp_add<0x4E,  0xF>(x[n]);
#pragma unroll
    for (int n = 0; n < N; ++n) x[n] = dpp_add<0x141, 0xF>(x[n]);
#pragma unroll
    for (int n = 0; n < N; ++n) x[n] = dpp_add<0x140, 0xF>(x[n]);
#pragma unroll
    for (int n = 0; n < N; ++n) x[n] = dpp_add<0x142, 0xA>(x[n]);
#pragma unroll
    for (int n = 0; n < N; ++n) x[n] = dpp_add<0x143, 0xC>(x[n]);
#pragma unroll
    for (int n = 0; n < N; ++n)
        x[n] = __int_as_float(__builtin_amdgcn_readlane(__float_as_int(x[n]), 63));
}

__device__ __forceinline__ float dot4v(const float4& a, const float4& b) {
    float t0 = a.x * b.x; t0 = fmaf(a.y, b.y, t0);
    float t1 = a.z * b.z; t1 = fmaf(a.w, b.w, t1);
    return t0 + t1;
}

// ---------------- Kernel 1: GEMM, 4 rows x ONE matrix per block (validated r7) ----------------
__global__ __launch_bounds__(256) void prep_kernel(
    const float* __restrict__ emb,
    const float* __restrict__ Wk, const float* __restrict__ bk,
    const float* __restrict__ Wv, const float* __restrict__ bv,
    float* __restrict__ K, float* __restrict__ V, float* __restrict__ USrev,
    float* __restrict__ out, int T)
{
    const int tid = threadIdx.x;
    const int bid = blockIdx.x;
    const int NBLK = (T / 4) * 2;
    if (bid >= NBLK) {
        const int PADS = ((T + 63) / 64) * 64;
        for (int i = tid; i < (PADS - T) * DK; i += 256) USrev[(size_t)T * DK + i] = 0.f;
        out[tid] = 0.f;
        return;
    }
    const int mat = bid & 1;
    const int r0  = (bid >> 1) * 4;

    __shared__ float se[4][D_EMB];
    __shared__ float s_red[4][4];

    const float4* emb4 = reinterpret_cast<const float4*>(emb);
#pragma unroll
    for (int r = 0; r < 4; ++r) {
        if (tid < D_EMB / 4)
            reinterpret_cast<float4*>(se[r])[tid] = emb4[(size_t)(r0 + r) * (D_EMB / 4) + tid];
    }
    __syncthreads();

    const float* Wp = mat ? Wv : Wk;
    const float* bp = mat ? bv : bk;
    const int j = tid;

    float a0 = 0.f, a1 = 0.f, a2 = 0.f, a3 = 0.f;
    float c0 = Wp[j],        c1 = Wp[j + DK],     c2 = Wp[j + 2*DK], c3 = Wp[j + 3*DK];
    float p0 = Wp[j + 4*DK], p1 = Wp[j + 5*DK],   p2 = Wp[j + 6*DK], p3 = Wp[j + 7*DK];

    for (int d = 0; d < D_EMB; d += 4) {
        int dn = d + 8; if (dn >= D_EMB) dn = 0;
        const float* wn = Wp + (size_t)dn * DK + j;
        float n0 = wn[0], n1 = wn[DK], n2 = wn[2*DK], n3 = wn[3*DK];

        float4 e0 = *reinterpret_cast<const float4*>(&se[0][d]);
        float4 e1 = *reinterpret_cast<const float4*>(&se[1][d]);
        float4 e2 = *reinterpret_cast<const float4*>(&se[2][d]);
        float4 e3 = *reinterpret_cast<const float4*>(&se[3][d]);

        a0 = fmaf(e0.x, c0, a0); a0 = fmaf(e0.y, c1, a0);
        a0 = fmaf(e0.z, c2, a0); a0 = fmaf(e0.w, c3, a0);
        a1 = fmaf(e1.x, c0, a1); a1 = fmaf(e1.y, c1, a1);
        a1 = fmaf(e1.z, c2, a1); a1 = fmaf(e1.w, c3, a1);
        a2 = fmaf(e2.x, c0, a2); a2 = fmaf(e2.y, c1, a2);
        a2 = fmaf(e2.z, c2, a2); a2 = fmaf(e2.w, c3, a2);
        a3 = fmaf(e3.x, c0, a3); a3 = fmaf(e3.y, c1, a3);
        a3 = fmaf(e3.z, c2, a3); a3 = fmaf(e3.w, c3, a3);

        c0 = p0; c1 = p1; c2 = p2; c3 = p3;
        p0 = n0; p1 = n1; p2 = n2; p3 = n3;
    }

    float bj = bp[j];
    float o0 = a0 + bj, o1 = a1 + bj, o2 = a2 + bj, o3 = a3 + bj;
    float* dst = mat ? V : K;
    dst[(size_t)(r0 + 0) * DK + j] = o0;
    dst[(size_t)(r0 + 1) * DK + j] = o1;
    dst[(size_t)(r0 + 2) * DK + j] = o2;
    dst[(size_t)(r0 + 3) * DK + j] = o3;

    if (mat == 0) {
        const int wave = tid >> 6, l = tid & 63;
        float red[4] = { o0*o0, o1*o1, o2*o2, o3*o3 };
        wave_allred_arr(red);
        if (l == 0) {
            s_red[wave][0] = red[0]; s_red[wave][1] = red[1];
            s_red[wave][2] = red[2]; s_red[wave][3] = red[3];
        }
        __syncthreads();
        float t0 = s_red[0][0] + s_red[1][0] + s_red[2][0] + s_red[3][0];
        float t1 = s_red[0][1] + s_red[1][1] + s_red[2][1] + s_red[3][1];
        float t2 = s_red[0][2] + s_red[1][2] + s_red[2][2] + s_red[3][2];
        float t3 = s_red[0][3] + s_red[1][3] + s_red[2][3] + s_red[3][3];
        USrev[(size_t)(T - 1 - (r0 + 0)) * DK + j] = o0 * (1.0f / fmaxf(sqrtf(t0), 1e-12f));
        USrev[(size_t)(T - 1 - (r0 + 1)) * DK + j] = o1 * (1.0f / fmaxf(sqrtf(t1), 1e-12f));
        USrev[(size_t)(T - 1 - (r0 + 2)) * DK + j] = o2 * (1.0f / fmaxf(sqrtf(t2), 1e-12f));
        USrev[(size_t)(T - 1 - (r0 + 3)) * DK + j] = o3 * (1.0f / fmaxf(sqrtf(t3), 1e-12f));
    }
}

// ------------- Kernel 2: U rows + gram + inversion + W = X^T (D) U + F1 + bias -------------
// 24 blocks: [0,NCS)=sentence, [NCS,NCS+NCP)=paraBackward, [NCS+NCP,..)=paraForward.
__global__ __launch_bounds__(256) void graminv_kernel(
    const float* __restrict__ K, const float* __restrict__ V,
    const float* __restrict__ USrev,
    float* __restrict__ UPrev, float* __restrict__ UPfwd,
    float* __restrict__ PV, float* __restrict__ SVv,
    float* __restrict__ AinvT, float* __restrict__ Wall,
    float* __restrict__ F1, float* __restrict__ biasF,
    int P, int NCS, int NCP)
{
    __shared__ float sU[64 * 257];
    __shared__ float sA[64 * 65];
    __shared__ float sX[64 * 65];
    __shared__ float s_sv[64];
    __shared__ float s_pd[64];
    __shared__ float4 s_f1[4];          // per-wave F1 partials, indexed [wave], lane-held
    __shared__ float4 s_f1w[4][64];
    const int tid = threadIdx.x, wv = tid >> 6, l = tid & 63;
    const int bid = blockIdx.x;
    int type, m;
    if (bid < NCS)            { type = 0; m = bid; }
    else if (bid < NCS + NCP) { type = 1; m = bid - NCS; }
    else                      { type = 2; m = bid - NCS - NCP; }

    if (tid < 64) s_pd[tid] = powf(P_DECAY, (float)tid);

    float4 f1p = make_float4(0.f, 0.f, 0.f, 0.f);

    // --- phase A: fill sU rows (64 x 256, stride 257) ---
    if (type == 0) {
        const float4* U4 = reinterpret_cast<const float4*>(USrev) + (size_t)m * 4096;
        for (int idx = tid; idx < 4096; idx += 256) {
            float4 t = U4[idx];
            int row = idx >> 6, c4 = (idx & 63) << 2;
            float* b = &sU[row * 257 + c4];
            b[0] = t.x; b[1] = t.y; b[2] = t.z; b[3] = t.w;
        }
    } else if (type == 1) {
        const float4* K4 = reinterpret_cast<const float4*>(K);
        for (int ii = 0; ii < 16; ++ii) {
            int i = wv * 16 + ii;
            int p = P - 1 - (64 * m + i);
            float4 u = make_float4(0.f, 0.f, 0.f, 0.f);
            if (p >= 0) {
                float4 pk = make_float4(0.f, 0.f, 0.f, 0.f);
#pragma unroll
                for (int s = 0; s < 5; ++s) {
                    float4 k4 = K4[(size_t)(5 * p + s) * 64 + l];
                    pk.x += k4.x; pk.y += k4.y; pk.z += k4.z; pk.w += k4.w;
                }
                pk.x *= 0.2f; pk.y *= 0.2f; pk.z *= 0.2f; pk.w *= 0.2f;
                float red[1] = { dot4v(pk, pk) };
                wave_allred_arr(red);
                float inv = 1.0f / fmaxf(sqrtf(red[0]), 1e-12f);
                u = make_float4(pk.x * inv, pk.y * inv, pk.z * inv, pk.w * inv);
            }
            float* b = &sU[i * 257 + 4 * l];
            b[0] = u.x; b[1] = u.y; b[2] = u.z; b[3] = u.w;
            reinterpret_cast<float4*>(UPrev)[(size_t)(64 * m + i) * 64 + l] = u;
        }
    } else {
        const float4* K4 = reinterpret_cast<const float4*>(K);
        const float4* V4 = reinterpret_cast<const float4*>(V);
        for (int ii = 0; ii < 16; ++ii) {
            int i = wv * 16 + ii;
            int p = 64 * m + i;
            float4 u = make_float4(0.f, 0.f, 0.f, 0.f);
            float sv = 0.f;
            if (p < P) {
                float4 pk = make_float4(0.f, 0.f, 0.f, 0.f);
                float4 pv = make_float4(0.f, 0.f, 0.f, 0.f);
#pragma unroll
                for (int s = 0; s < 5; ++s) {
                    float4 k4 = K4[(size_t)(5 * p + s) * 64 + l];
                    float4 v4 = V4[(size_t)(5 * p + s) * 64 + l];
                    pk.x += k4.x; pk.y += k4.y; pk.z += k4.z; pk.w += k4.w;
                    pv.x += v4.x; pv.y += v4.y; pv.z += v4.z; pv.w += v4.w;
                }
                pk.x *= 0.2f; pk.y *= 0.2f; pk.z *= 0.2f; pk.w *= 0.2f;
                pv.x *= 0.2f; pv.y *= 0.2f; pv.z *= 0.2f; pv.w *= 0.2f;
                reinterpret_cast<float4*>(PV)[(size_t)p * 64 + l] = pv;
                float red[2] = { dot4v(pk, pk), pv.x + pv.y + pv.z + pv.w };
                wave_allred_arr(red);
                float inv = 1.0f / fmaxf(sqrtf(red[0]), 1e-12f);
                u = make_float4(pk.x * inv, pk.y * inv, pk.z * inv, pk.w * inv);
                sv = red[1];
            }
            float* b = &sU[i * 257 + 4 * l];
            b[0] = u.x; b[1] = u.y; b[2] = u.z; b[3] = u.w;
            reinterpret_cast<float4*>(UPfwd)[(size_t)(64 * m + i) * 64 + l] = u;
            if (l == 0) { s_sv[i] = sv; SVv[64 * m + i] = sv; }
            // F1 partial: pd^{63-i} * sv_i * u_i  (sv uniform after allred)
            float f = powf(P_DECAY, (float)(63 - i)) * sv;
            f1p.x = fmaf(f, u.x, f1p.x); f1p.y = fmaf(f, u.y, f1p.y);
            f1p.z = fmaf(f, u.z, f1p.z); f1p.w = fmaf(f, u.w, f1p.w);
        }
        s_f1w[wv][l] = f1p;
    }
    __syncthreads();

    if (type == 2 && wv == 0) {
        float4 a = s_f1w[0][l], b = s_f1w[1][l], c = s_f1w[2][l], d = s_f1w[3][l];
        float4 tot = make_float4(a.x+b.x+c.x+d.x, a.y+b.y+c.y+d.y,
                                 a.z+b.z+c.z+d.z, a.w+b.w+c.w+d.w);
        reinterpret_cast<float4*>(F1)[(size_t)m * 64 + l] = tot;
    }

    // --- phase B: gram 4x4 register tile (scalar LDS reads) ---
    const int tr = tid & 15, tcg = tid >> 4;
    const int i0 = tr * 4, j0 = tcg * 4;
    {
        float g00=0,g01=0,g02=0,g03=0, g10=0,g11=0,g12=0,g13=0;
        float g20=0,g21=0,g22=0,g23=0, g30=0,g31=0,g32=0,g33=0;
        for (int k = 0; k < 256; ++k) {
            float aa0 = sU[(i0    ) * 257 + k];
            float aa1 = sU[(i0 + 1) * 257 + k];
            float aa2 = sU[(i0 + 2) * 257 + k];
            float aa3 = sU[(i0 + 3) * 257 + k];
            float bb0 = sU[(j0    ) * 257 + k];
            float bb1 = sU[(j0 + 1) * 257 + k];
            float bb2 = sU[(j0 + 2) * 257 + k];
            float bb3 = sU[(j0 + 3) * 257 + k];
            g00 = fmaf(aa0, bb0, g00); g01 = fmaf(aa0, bb1, g01);
            g02 = fmaf(aa0, bb2, g02); g03 = fmaf(aa0, bb3, g03);
            g10 = fmaf(aa1, bb0, g10); g11 = fmaf(aa1, bb1, g11);
            g12 = fmaf(aa1, bb2, g12); g13 = fmaf(aa1, bb3, g13);
            g20 = fmaf(aa2, bb0, g20); g21 = fmaf(aa2, bb1, g21);
            g22 = fmaf(aa2, bb2, g22); g23 = fmaf(aa2, bb3, g23);
            g30 = fmaf(aa3, bb0, g30); g31 = fmaf(aa3, bb1, g31);
            g32 = fmaf(aa3, bb2, g32); g33 = fmaf(aa3, bb3, g33);
        }
        float gt[4][4] = { {g00,g01,g02,g03}, {g10,g11,g12,g13},
                           {g20,g21,g22,g23}, {g30,g31,g32,g33} };
#pragma unroll
        for (int r = 0; r < 4; ++r)
#pragma unroll
            for (int c = 0; c < 4; ++c) {
                int gi = i0 + r, gj = j0 + c;
                float val = 0.f;
                if (gj < gi) {
                    val = ALPHA * gt[r][c];
                    if (type == 2) val *= s_pd[gi - gj];
                }
                sA[gi * 65 + gj] = val;
            }
    }
    __syncthreads();

    // --- bias (type 2): bias_i = (1/alpha) * sum_j A_ij sv_j ---
    if (type == 2 && wv == 0) {
        float dotb = 0.f;
#pragma unroll
        for (int jj = 0; jj < 64; ++jj)
            dotb = fmaf(sA[l * 65 + jj], s_sv[jj], dotb);
        biasF[m * 64 + l] = dotb * (1.0f / ALPHA);
    }

    // --- phase C: X = (I+A)^{-1}, wave-staged forward substitution ---
    {
        const int base = wv * 16;
        float x[16];
#pragma unroll
        for (int r = 0; r < 16; ++r) x[r] = (base + r == l) ? 1.f : 0.f;
        for (int s = 0; s < 4; ++s) {
            if (wv == s) {
#pragma unroll
                for (int i = 1; i < 16; ++i)
#pragma unroll
                    for (int jj = 0; jj < 16; ++jj)
                        if (jj < i)
                            x[i] = fmaf(-sA[(base + i) * 65 + (base + jj)], x[jj], x[i]);
#pragma unroll
                for (int r = 0; r < 16; ++r) sX[(base + r) * 65 + l] = x[r];
            }
            __syncthreads();
            if (wv > s) {
#pragma unroll
                for (int i = 0; i < 16; ++i) {
                    float xi = sX[(s * 16 + i) * 65 + l];
#pragma unroll
                    for (int r = 0; r < 16; ++r)
                        x[r] = fmaf(-sA[(base + r) * 65 + (s * 16 + i)], xi, x[r]);
                }
            }
        }
    }
    __syncthreads();

    // --- store X (backward types only, for accum's c = Xb) ---
    if (type != 2) {
        float* dstA = AinvT + (size_t)bid * 4096;
        for (int idx = tid; idx < 4096; idx += 256) {
            int jcol = idx >> 6, irow = idx & 63;
            dstA[idx] = sX[irow * 65 + jcol];
        }
    }

    // --- phase D: W[j,:] = sum_i (scale_i) X[i][j] u_i[:]  (scale = pd[63-i] for fwd) ---
    // thread: rows j in {tr*4..+3}, cols {tcg*16..+15}
    {
        const int c0 = tcg * 16;
        float wacc[4][16];
#pragma unroll
        for (int r = 0; r < 4; ++r)
#pragma unroll
            for (int c = 0; c < 16; ++c) wacc[r][c] = 0.f;
        for (int i = 0; i < 64; ++i) {
            float x0 = sX[i * 65 + i0    ];
            float x1 = sX[i * 65 + i0 + 1];
            float x2 = sX[i * 65 + i0 + 2];
            float x3 = sX[i * 65 + i0 + 3];
            if (type == 2) {
                float f = s_pd[63 - i];
                x0 *= f; x1 *= f; x2 *= f; x3 *= f;
            }
#pragma unroll
            for (int c = 0; c < 16; ++c) {
                float u = sU[i * 257 + c0 + c];
                wacc[0][c] = fmaf(x0, u, wacc[0][c]);
                wacc[1][c] = fmaf(x1, u, wacc[1][c]);
                wacc[2][c] = fmaf(x2, u, wacc[2][c]);
                wacc[3][c] = fmaf(x3, u, wacc[3][c]);
            }
        }
        float* dstW = Wall + (size_t)bid * 16384;
#pragma unroll
        for (int r = 0; r < 4; ++r) {
#pragma unroll
            for (int c4 = 0; c4 < 4; ++c4) {
                float4 t = make_float4(wacc[r][c4*4], wacc[r][c4*4+1],
                                       wacc[r][c4*4+2], wacc[r][c4*4+3]);
                reinterpret_cast<float4*>(dstW)[((i0 + r) * 256 + c0 + c4*4) >> 2] = t;
            }
        }
    }
}

// ------------- Kernel 3: solver, 2 blocks x 512 threads, 1 barrier/chunk -------------
__global__ __launch_bounds__(512) void solve_kernel(
    const float* __restrict__ USrev, const float* __restrict__ UPrev,
    const float* __restrict__ UPfwd, const float* __restrict__ Wall,
    const float* __restrict__ F1, const float* __restrict__ biasF,
    const float* __restrict__ q,
    float* __restrict__ BS, float* __restrict__ BPB1, float* __restrict__ BPB2,
    float* __restrict__ gscal, int NCS, int NCP)
{
    __shared__ float4 s_part[2][8][64], s_part2[2][8][64];
    __shared__ float s_powd[65];
    const int tid = threadIdx.x, wave = tid >> 6, l = tid & 63;
    const int wb = wave * 8;
    if (tid <= 64) s_powd[tid] = powf(P_DECAY, (float)tid);

    float4 q4 = reinterpret_cast<const float4*>(q)[l];
    float qs[1] = { dot4v(q4, q4) };
    wave_allred_arr(qs);
    float qinv = 1.0f / fmaxf(sqrtf(qs[0]), 1e-12f);
    float4 qn = make_float4(q4.x * qinv, q4.y * qinv, q4.z * qinv, q4.w * qinv);
    __syncthreads();

    const float4* W4 = reinterpret_cast<const float4*>(Wall);

    if (blockIdx.x == 0) {
        // ============ sentence backward: 16 chunks ============
        float4 w1 = qn;
        const float4* U4 = reinterpret_cast<const float4*>(USrev);
        float4 curU[8];
#pragma unroll
        for (int r = 0; r < 8; ++r) curU[r] = U4[(size_t)(wb + r) * 64 + l];
        for (int m = 0; m < NCS; ++m) {
            float4 curW[8];
#pragma unroll
            for (int r = 0; r < 8; ++r)
                curW[r] = W4[(size_t)m * 4096 + (size_t)(wb + r) * 64 + l];
            float4 nxtU[8];
            if (m + 1 < NCS) {
#pragma unroll
                for (int r = 0; r < 8; ++r)
                    nxtU[r] = U4[(size_t)(m + 1) * 4096 + (size_t)(wb + r) * 64 + l];
            }
            float d[8];
#pragma unroll
            for (int r = 0; r < 8; ++r) d[r] = dot4v(curU[r], w1);
            wave_allred_arr(d);
            if (l == 0) {
#pragma unroll
                for (int r = 0; r < 8; ++r) BS[m * 64 + wb + r] = d[r];
            }
            float4 part = make_float4(0.f, 0.f, 0.f, 0.f);
#pragma unroll
            for (int r = 0; r < 8; ++r) {
                part.x = fmaf(d[r], curW[r].x, part.x);
                part.y = fmaf(d[r], curW[r].y, part.y);
                part.z = fmaf(d[r], curW[r].z, part.z);
                part.w = fmaf(d[r], curW[r].w, part.w);
            }
            s_part[m & 1][wave][l] = part;
            __syncthreads();
            float4 s = make_float4(0.f, 0.f, 0.f, 0.f);
#pragma unroll
            for (int w = 0; w < 8; ++w) {
                float4 p = s_part[m & 1][w][l];
                s.x += p.x; s.y += p.y; s.z += p.z; s.w += p.w;
            }
            w1.x = fmaf(-ALPHA, s.x, w1.x); w1.y = fmaf(-ALPHA, s.y, w1.y);
            w1.z = fmaf(-ALPHA, s.z, w1.z); w1.w = fmaf(-ALPHA, s.w, w1.w);
            if (m + 1 < NCS) {
#pragma unroll
                for (int r = 0; r < 8; ++r) curU[r] = nxtU[r];
            }
        }
    } else {
        // ============ paragraph backward (dual RHS): NCP chunks ============
        {
            float4 w1 = qn;
            float4 w2 = make_float4(1.f, 1.f, 1.f, 1.f);
            const float4* U4 = reinterpret_cast<const float4*>(UPrev);
            float4 curU[8];
#pragma unroll
            for (int r = 0; r < 8; ++r) curU[r] = U4[(size_t)(wb + r) * 64 + l];
            for (int m = 0; m < NCP; ++m) {
                float4 curW[8];
#pragma unroll
                for (int r = 0; r < 8; ++r)
                    curW[r] = W4[(size_t)(NCS + m) * 4096 + (size_t)(wb + r) * 64 + l];
                float4 nxtU[8];
                if (m + 1 < NCP) {
#pragma unroll
                    for (int r = 0; r < 8; ++r)
                        nxtU[r] = U4[(size_t)(m + 1) * 4096 + (size_t)(wb + r) * 64 + l];
                }
                float d[16];
#pragma unroll
                for (int r = 0; r < 8; ++r) {
                    d[r]     = dot4v(curU[r], w1);
                    d[8 + r] = dot4v(curU[r], w2);
                }
                wave_allred_arr(d);
                if (l == 0) {
#pragma unroll
                    for (int r = 0; r < 8; ++r) {
                        BPB1[m * 64 + wb + r] = d[r];
                        BPB2[m * 64 + wb + r] = d[8 + r];
                    }
                }
                float4 p1 = make_float4(0.f,0.f,0.f,0.f), p2 = make_float4(0.f,0.f,0.f,0.f);
#pragma unroll
                for (int r = 0; r < 8; ++r) {
                    p1.x = fmaf(d[r], curW[r].x, p1.x);   p1.y = fmaf(d[r], curW[r].y, p1.y);
                    p1.z = fmaf(d[r], curW[r].z, p1.z);   p1.w = fmaf(d[r], curW[r].w, p1.w);
                    p2.x = fmaf(d[8+r], curW[r].x, p2.x); p2.y = fmaf(d[8+r], curW[r].y, p2.y);
                    p2.z = fmaf(d[8+r], curW[r].z, p2.z); p2.w = fmaf(d[8+r], curW[r].w, p2.w);
                }
                s_part[m & 1][wave][l] = p1; s_part2[m & 1][wave][l] = p2;
                __syncthreads();
                float4 s1 = make_float4(0.f,0.f,0.f,0.f), s2 = make_float4(0.f,0.f,0.f,0.f);
#pragma unroll
                for (int w = 0; w < 8; ++w) {
                    float4 a = s_part[m & 1][w][l];  float4 b = s_part2[m & 1][w][l];
                    s1.x += a.x; s1.y += a.y; s1.z += a.z; s1.w += a.w;
                    s2.x += b.x; s2.y += b.y; s2.z += b.z; s2.w += b.w;
                }
                w1.x = fmaf(-ALPHA, s1.x, w1.x); w1.y = fmaf(-ALPHA, s1.y, w1.y);
                w1.z = fmaf(-ALPHA, s1.z, w1.z); w1.w = fmaf(-ALPHA, s1.w, w1.w);
                w2.x = fmaf(-ALPHA, s2.x, w2.x); w2.y = fmaf(-ALPHA, s2.y, w2.y);
                w2.z = fmaf(-ALPHA, s2.z, w2.z); w2.w = fmaf(-ALPHA, s2.w, w2.w);
                if (m + 1 < NCP) {
#pragma unroll
                    for (int r = 0; r < 8; ++r) curU[r] = nxtU[r];
                }
            }
        }
        __syncthreads();
        // ============ paragraph forward: NCP chunks ============
        float4 y = make_float4(0.f, 0.f, 0.f, 0.f);
        {
            const float4* U4 = reinterpret_cast<const float4*>(UPfwd);
            float4 curU[8];
#pragma unroll
            for (int r = 0; r < 8; ++r) curU[r] = U4[(size_t)(wb + r) * 64 + l];
            for (int m = 0; m < NCP; ++m) {
                float4 curW[8];
#pragma unroll
                for (int r = 0; r < 8; ++r)
                    curW[r] = W4[(size_t)(NCS + NCP + m) * 4096 + (size_t)(wb + r) * 64 + l];
                float biasr[8];
#pragma unroll
                for (int r = 0; r < 8; ++r) biasr[r] = biasF[m * 64 + wb + r];
                float4 f1 = reinterpret_cast<const float4*>(F1)[(size_t)m * 64 + l];
                float4 nxtU[8];
                if (m + 1 < NCP) {
#pragma unroll
                    for (int r = 0; r < 8; ++r)
                        nxtU[r] = U4[(size_t)(m + 1) * 4096 + (size_t)(wb + r) * 64 + l];
                }
                float d[8];
#pragma unroll
                for (int r = 0; r < 8; ++r) d[r] = dot4v(curU[r], y);
                wave_allred_arr(d);
                // b'_j = pd[j+1]*raw_j + bias_j
#pragma unroll
                for (int r = 0; r < 8; ++r)
                    d[r] = fmaf(s_powd[wb + r + 1], d[r], biasr[r]);
                float4 part = make_float4(0.f, 0.f, 0.f, 0.f);
#pragma unroll
                for (int r = 0; r < 8; ++r) {
                    part.x = fmaf(d[r], curW[r].x, part.x);
                    part.y = fmaf(d[r], curW[r].y, part.y);
                    part.z = fmaf(d[r], curW[r].z, part.z);
                    part.w = fmaf(d[r], curW[r].w, part.w);
                }
                s_part[m & 1][wave][l] = part;
                __syncthreads();
                float4 s = make_float4(0.f, 0.f, 0.f, 0.f);
#pragma unroll
                for (int w = 0; w < 8; ++w) {
                    float4 p = s_part[m & 1][w][l];
                    s.x += p.x; s.y += p.y; s.z += p.z; s.w += p.w;
                }
                float d64 = s_powd[64];
                y.x = fmaf(d64, y.x, fmaf(-ALPHA, s.x, f1.x));
                y.y = fmaf(d64, y.y, fmaf(-ALPHA, s.y, f1.y));
                y.z = fmaf(d64, y.z, fmaf(-ALPHA, s.z, f1.z));
                y.w = fmaf(d64, y.w, fmaf(-ALPHA, s.w, f1.w));
                if (m + 1 < NCP) {
#pragma unroll
                    for (int r = 0; r < 8; ++r) curU[r] = nxtU[r];
                }
            }
        }
        float fin[2] = { dot4v(y, y), dot4v(qn, y) };
        wave_allred_arr(fin);
        if (tid == 0) gscal[0] = fin[1] / fmaxf(sqrtf(fin[0]), 2.56e-10f);
    }
}

// ------------- Kernel 4: c = X b, then weighted accumulation -> atomic combine -------------
__global__ __launch_bounds__(256) void accum_kernel(
    const float* __restrict__ V, const float* __restrict__ PV,
    const float* __restrict__ AinvT,
    const float* __restrict__ BS, const float* __restrict__ BPB1,
    const float* __restrict__ BPB2, const float* __restrict__ gscal,
    float* __restrict__ out, int T, int P, int NCS, int NCP)
{
    __shared__ float s_b[64], s_cp[4][64], wc[64];
    const int b = blockIdx.x, t = threadIdx.x;
    const float* src; const float* B; int i0, realN, chunk; float decay;
    if (b < NCS)            { src = V;  B = BS;   i0 = b * 64;               realN = T; decay = S_DECAY; chunk = b; }
    else if (b < NCS + NCP) { src = PV; B = BPB1; i0 = (b - NCS) * 64;       realN = P; decay = P_DECAY; chunk = b; }
    else                    { src = PV; B = BPB2; i0 = (b - NCS - NCP) * 64; realN = P; decay = P_DECAY; chunk = b - NCP; }
    if (t < 64) s_b[t] = B[(i0 & ~63) + t - i0 + i0];   // = B[chunk-local offset + t]
    // note: i0 is chunk_index*64 within its own B array:
    if (t < 64) s_b[t] = B[((b < NCS) ? b : (b < NCS + NCP ? b - NCS : b - NCS - NCP)) * 64 + t];
    __syncthreads();
    // c = X b : thread (part = t>>6, k = t&63): partial over j in [16*part, 16*part+16)
    {
        const int part = t >> 6, k = t & 63;
        const float* Xc = AinvT + (size_t)chunk * 4096;
        float cp = 0.f;
#pragma unroll
        for (int jj = 0; jj < 16; ++jj) {
            int j = part * 16 + jj;
            cp = fmaf(Xc[j * 64 + k], s_b[j], cp);
        }
        s_cp[part][k] = cp;
    }
    __syncthreads();
    if (t < 64) {
        float c = s_cp[0][t] + s_cp[1][t] + s_cp[2][t] + s_cp[3][t];
        wc[t] = powf(decay, (float)(i0 + t)) * c;
    }
    __syncthreads();
    const int k = t;
    float acc = 0.f;
    for (int ii = 0; ii < 64; ++ii) {
        int i = i0 + ii;
        if (i < realN)
            acc = fmaf(wc[ii], src[(size_t)(realN - 1 - i) * DK + k], acc);
    }
    float wlev;
    if (b < NCS)            wlev = 0.2f;
    else if (b < NCS + NCP) wlev = 0.3f;
    else                    wlev = (0.5f / 256.0f) * gscal[0];
    atomicAdd(&out[k], wlev * acc);
}

extern "C" void kernel_launch(void* const* d_in, const int* in_sizes, int n_in,
                              void* d_out, int out_size, void* d_ws, size_t ws_size,
                              hipStream_t stream) {
    const float* emb = (const float*)d_in[0];
    const float* q   = (const float*)d_in[1];
    const float* Wk  = (const float*)d_in[2];
    const float* bk  = (const float*)d_in[3];
    const float* Wv  = (const float*)d_in[4];
    const float* bv  = (const float*)d_in[5];

    const int T = in_sizes[0] / D_EMB;        // 1000
    const int P = T / 5;                      // 200
    const int NCS  = (T + 63) / 64;           // 16
    const int NCP  = (P + 63) / 64;           // 4
    const int PADS = NCS * 64;                // 1024
    const int PADP = NCP * 64;                // 256
    const int NCH  = NCS + 2 * NCP;           // 24

    float* ws    = (float*)d_ws;
    float* K     = ws;                               // T*256
    float* V     = K     + (size_t)T * DK;           // T*256
    float* PV    = V     + (size_t)T * DK;           // PADP*256
    float* USrev = PV    + (size_t)PADP * DK;        // PADS*256
    float* UPrev = USrev + (size_t)PADS * DK;        // PADP*256
    float* UPfwd = UPrev + (size_t)PADP * DK;        // PADP*256
    float* SVv   = UPfwd + (size_t)PADP * DK;        // PADP
    float* AinvT = SVv   + PADP;                     // NCH*4096 (only first NCS+NCP used)
    float* Wall  = AinvT + (size_t)NCH * 4096;       // NCH*16384
    float* F1    = Wall  + (size_t)NCH * 16384;      // NCP*256
    float* biasF = F1    + (size_t)NCP * 256;        // PADP
    float* BS    = biasF + PADP;                     // PADS
    float* BPB1  = BS    + PADS;                     // PADP
    float* BPB2  = BPB1  + PADP;                     // PADP
    float* gscal = BPB2  + PADP;                     // 4

    prep_kernel<<<(T / 4) * 2 + 1, 256, 0, stream>>>(emb, Wk, bk, Wv, bv,
                                                     K, V, USrev, (float*)d_out, T);
    graminv_kernel<<<NCH, 256, 0, stream>>>(K, V, USrev, UPrev, UPfwd,
                                            PV, SVv, AinvT, Wall, F1, biasF, P, NCS, NCP);
    solve_kernel<<<2, 512, 0, stream>>>(USrev, UPrev, UPfwd, Wall, F1, biasF, q,
                                        BS, BPB1, BPB2, gscal, NCS, NCP);
    accum_kernel<<<NCH, 256, 0, stream>>>(V, PV, AinvT, BS, BPB1, BPB2, gscal,
                                          (float*)d_out, T, P, NCS, NCP);
}

// Round 9
// 185.977 us; speedup vs baseline: 1.0667x; 1.0667x over previous
//
#include <hip/hip_runtime.h>
#include <hip/hip_bf16.h>

#define ALPHA   0.1f
#define S_DECAY 0.95f
#define P_DECAY 0.99f
#define D_EMB   768
#define DK      256

// ---- DPP wave-64 reduction helpers (validated rounds 1-8) ----
template<int ctrl, int row_mask>
__device__ __forceinline__ float dpp_add(float x) {
    int y = __builtin_amdgcn_update_dpp(0, __float_as_int(x), ctrl, row_mask, 0xF, true);
    return x + __int_as_float(y);
}

template<int N>
__device__ __forceinline__ void wave_allred_arr(float (&x)[N]) {
#pragma unroll
    for (int n = 0; n < N; ++n) x[n] = dpp_add<0xB1,  0xF>(x[n]);
#pragma unroll
    for (int n = 0; n < N; ++n) x[n] = dpp_add<0x4E,  0xF>(x[n]);
#pragma unroll
    for (int n = 0; n < N; ++n) x[n] = dpp_add<0x141, 0xF>(x[n]);
#pragma unroll
    for (int n = 0; n < N; ++n) x[n] = dpp_add<0x140, 0xF>(x[n]);
#pragma unroll
    for (int n = 0; n < N; ++n) x[n] = dpp_add<0x142, 0xA>(x[n]);
#pragma unroll
    for (int n = 0; n < N; ++n) x[n] = dpp_add<0x143, 0xC>(x[n]);
#pragma unroll
    for (int n = 0; n < N; ++n)
        x[n] = __int_as_float(__builtin_amdgcn_readlane(__float_as_int(x[n]), 63));
}

__device__ __forceinline__ float dot4v(const float4& a, const float4& b) {
    float t0 = a.x * b.x; t0 = fmaf(a.y, b.y, t0);
    float t1 = a.z * b.z; t1 = fmaf(a.w, b.w, t1);
    return t0 + t1;
}

__device__ __forceinline__ float rl(float x, int lane) {
    return __int_as_float(__builtin_amdgcn_readlane(__float_as_int(x), lane));
}

// ---------------- Kernel 1: GEMM, 4 rows x ONE matrix per block (validated r7/r8) ----------------
__global__ __launch_bounds__(256) void prep_kernel(
    const float* __restrict__ emb,
    const float* __restrict__ Wk, const float* __restrict__ bk,
    const float* __restrict__ Wv, const float* __restrict__ bv,
    float* __restrict__ K, float* __restrict__ V, float* __restrict__ USrev,
    float* __restrict__ out, int T)
{
    const int tid = threadIdx.x;
    const int bid = blockIdx.x;
    const int NBLK = (T / 4) * 2;
    if (bid >= NBLK) {
        const int PADS = ((T + 63) / 64) * 64;
        for (int i = tid; i < (PADS - T) * DK; i += 256) USrev[(size_t)T * DK + i] = 0.f;
        out[tid] = 0.f;
        return;
    }
    const int mat = bid & 1;
    const int r0  = (bid >> 1) * 4;

    __shared__ float se[4][D_EMB];
    __shared__ float s_red[4][4];

    const float4* emb4 = reinterpret_cast<const float4*>(emb);
#pragma unroll
    for (int r = 0; r < 4; ++r) {
        if (tid < D_EMB / 4)
            reinterpret_cast<float4*>(se[r])[tid] = emb4[(size_t)(r0 + r) * (D_EMB / 4) + tid];
    }
    __syncthreads();

    const float* Wp = mat ? Wv : Wk;
    const float* bp = mat ? bv : bk;
    const int j = tid;

    float a0 = 0.f, a1 = 0.f, a2 = 0.f, a3 = 0.f;
    float c0 = Wp[j],        c1 = Wp[j + DK],     c2 = Wp[j + 2*DK], c3 = Wp[j + 3*DK];
    float p0 = Wp[j + 4*DK], p1 = Wp[j + 5*DK],   p2 = Wp[j + 6*DK], p3 = Wp[j + 7*DK];

    for (int d = 0; d < D_EMB; d += 4) {
        int dn = d + 8; if (dn >= D_EMB) dn = 0;
        const float* wn = Wp + (size_t)dn * DK + j;
        float n0 = wn[0], n1 = wn[DK], n2 = wn[2*DK], n3 = wn[3*DK];

        float4 e0 = *reinterpret_cast<const float4*>(&se[0][d]);
        float4 e1 = *reinterpret_cast<const float4*>(&se[1][d]);
        float4 e2 = *reinterpret_cast<const float4*>(&se[2][d]);
        float4 e3 = *reinterpret_cast<const float4*>(&se[3][d]);

        a0 = fmaf(e0.x, c0, a0); a0 = fmaf(e0.y, c1, a0);
        a0 = fmaf(e0.z, c2, a0); a0 = fmaf(e0.w, c3, a0);
        a1 = fmaf(e1.x, c0, a1); a1 = fmaf(e1.y, c1, a1);
        a1 = fmaf(e1.z, c2, a1); a1 = fmaf(e1.w, c3, a1);
        a2 = fmaf(e2.x, c0, a2); a2 = fmaf(e2.y, c1, a2);
        a2 = fmaf(e2.z, c2, a2); a2 = fmaf(e2.w, c3, a2);
        a3 = fmaf(e3.x, c0, a3); a3 = fmaf(e3.y, c1, a3);
        a3 = fmaf(e3.z, c2, a3); a3 = fmaf(e3.w, c3, a3);

        c0 = p0; c1 = p1; c2 = p2; c3 = p3;
        p0 = n0; p1 = n1; p2 = n2; p3 = n3;
    }

    float bj = bp[j];
    float o0 = a0 + bj, o1 = a1 + bj, o2 = a2 + bj, o3 = a3 + bj;
    float* dst = mat ? V : K;
    dst[(size_t)(r0 + 0) * DK + j] = o0;
    dst[(size_t)(r0 + 1) * DK + j] = o1;
    dst[(size_t)(r0 + 2) * DK + j] = o2;
    dst[(size_t)(r0 + 3) * DK + j] = o3;

    if (mat == 0) {
        const int wave = tid >> 6, l = tid & 63;
        float red[4] = { o0*o0, o1*o1, o2*o2, o3*o3 };
        wave_allred_arr(red);
        if (l == 0) {
            s_red[wave][0] = red[0]; s_red[wave][1] = red[1];
            s_red[wave][2] = red[2]; s_red[wave][3] = red[3];
        }
        __syncthreads();
        float t0 = s_red[0][0] + s_red[1][0] + s_red[2][0] + s_red[3][0];
        float t1 = s_red[0][1] + s_red[1][1] + s_red[2][1] + s_red[3][1];
        float t2 = s_red[0][2] + s_red[1][2] + s_red[2][2] + s_red[3][2];
        float t3 = s_red[0][3] + s_red[1][3] + s_red[2][3] + s_red[3][3];
        USrev[(size_t)(T - 1 - (r0 + 0)) * DK + j] = o0 * (1.0f / fmaxf(sqrtf(t0), 1e-12f));
        USrev[(size_t)(T - 1 - (r0 + 1)) * DK + j] = o1 * (1.0f / fmaxf(sqrtf(t1), 1e-12f));
        USrev[(size_t)(T - 1 - (r0 + 2)) * DK + j] = o2 * (1.0f / fmaxf(sqrtf(t2), 1e-12f));
        USrev[(size_t)(T - 1 - (r0 + 3)) * DK + j] = o3 * (1.0f / fmaxf(sqrtf(t3), 1e-12f));
    }
}

// ------------- Kernel 2: U rows + gram (float4, lower-tri only) + inversion + F1 + bias -------------
// 24 blocks: [0,NCS)=sentence, [NCS,NCS+NCP)=paraBackward, [NCS+NCP,..)=paraForward.
#define SU_STRIDE 260
__global__ __launch_bounds__(256) void graminv_kernel(
    const float* __restrict__ K, const float* __restrict__ V,
    const float* __restrict__ USrev,
    float* __restrict__ UPrev, float* __restrict__ UPfwd,
    float* __restrict__ PV, float* __restrict__ SVv,
    float* __restrict__ AinvT, float* __restrict__ F1, float* __restrict__ biasF,
    int P, int NCS, int NCP)
{
    __shared__ float sU[64 * SU_STRIDE];
    __shared__ float sA[64 * 65];
    __shared__ float sX[64 * 65];
    __shared__ float s_sv[64];
    __shared__ float s_pd[64];
    __shared__ float4 s_f1w[4][64];
    const int tid = threadIdx.x, wv = tid >> 6, l = tid & 63;
    const int bid = blockIdx.x;
    int type, m;
    if (bid < NCS)            { type = 0; m = bid; }
    else if (bid < NCS + NCP) { type = 1; m = bid - NCS; }
    else                      { type = 2; m = bid - NCS - NCP; }

    if (tid < 64) s_pd[tid] = powf(P_DECAY, (float)tid);

    float4 f1p = make_float4(0.f, 0.f, 0.f, 0.f);

    // --- phase A: fill sU rows (64 x 256, row stride 260 -> aligned float4) ---
    if (type == 0) {
        const float4* U4 = reinterpret_cast<const float4*>(USrev) + (size_t)m * 4096;
        for (int idx = tid; idx < 4096; idx += 256) {
            float4 t = U4[idx];
            int row = idx >> 6, c4 = (idx & 63) << 2;
            *reinterpret_cast<float4*>(&sU[row * SU_STRIDE + c4]) = t;
        }
    } else if (type == 1) {
        const float4* K4 = reinterpret_cast<const float4*>(K);
        for (int ii = 0; ii < 16; ++ii) {
            int i = wv * 16 + ii;
            int p = P - 1 - (64 * m + i);
            float4 u = make_float4(0.f, 0.f, 0.f, 0.f);
            if (p >= 0) {
                float4 pk = make_float4(0.f, 0.f, 0.f, 0.f);
#pragma unroll
                for (int s = 0; s < 5; ++s) {
                    float4 k4 = K4[(size_t)(5 * p + s) * 64 + l];
                    pk.x += k4.x; pk.y += k4.y; pk.z += k4.z; pk.w += k4.w;
                }
                pk.x *= 0.2f; pk.y *= 0.2f; pk.z *= 0.2f; pk.w *= 0.2f;
                float red[1] = { dot4v(pk, pk) };
                wave_allred_arr(red);
                float inv = 1.0f / fmaxf(sqrtf(red[0]), 1e-12f);
                u = make_float4(pk.x * inv, pk.y * inv, pk.z * inv, pk.w * inv);
            }
            *reinterpret_cast<float4*>(&sU[i * SU_STRIDE + 4 * l]) = u;
            reinterpret_cast<float4*>(UPrev)[(size_t)(64 * m + i) * 64 + l] = u;
        }
    } else {
        const float4* K4 = reinterpret_cast<const float4*>(K);
        const float4* V4 = reinterpret_cast<const float4*>(V);
        for (int ii = 0; ii < 16; ++ii) {
            int i = wv * 16 + ii;
            int p = 64 * m + i;
            float4 u = make_float4(0.f, 0.f, 0.f, 0.f);
            float sv = 0.f;
            if (p < P) {
                float4 pk = make_float4(0.f, 0.f, 0.f, 0.f);
                float4 pv = make_float4(0.f, 0.f, 0.f, 0.f);
#pragma unroll
                for (int s = 0; s < 5; ++s) {
                    float4 k4 = K4[(size_t)(5 * p + s) * 64 + l];
                    float4 v4 = V4[(size_t)(5 * p + s) * 64 + l];
                    pk.x += k4.x; pk.y += k4.y; pk.z += k4.z; pk.w += k4.w;
                    pv.x += v4.x; pv.y += v4.y; pv.z += v4.z; pv.w += v4.w;
                }
                pk.x *= 0.2f; pk.y *= 0.2f; pk.z *= 0.2f; pk.w *= 0.2f;
                pv.x *= 0.2f; pv.y *= 0.2f; pv.z *= 0.2f; pv.w *= 0.2f;
                reinterpret_cast<float4*>(PV)[(size_t)p * 64 + l] = pv;
                float red[2] = { dot4v(pk, pk), pv.x + pv.y + pv.z + pv.w };
                wave_allred_arr(red);
                float inv = 1.0f / fmaxf(sqrtf(red[0]), 1e-12f);
                u = make_float4(pk.x * inv, pk.y * inv, pk.z * inv, pk.w * inv);
                sv = red[1];
            }
            *reinterpret_cast<float4*>(&sU[i * SU_STRIDE + 4 * l]) = u;
            reinterpret_cast<float4*>(UPfwd)[(size_t)(64 * m + i) * 64 + l] = u;
            if (l == 0) { s_sv[i] = sv; SVv[64 * m + i] = sv; }
            float f = powf(P_DECAY, (float)(63 - i)) * sv;
            f1p.x = fmaf(f, u.x, f1p.x); f1p.y = fmaf(f, u.y, f1p.y);
            f1p.z = fmaf(f, u.z, f1p.z); f1p.w = fmaf(f, u.w, f1p.w);
        }
        s_f1w[wv][l] = f1p;
    }
    __syncthreads();

    if (type == 2 && wv == 0) {
        float4 a = s_f1w[0][l], b = s_f1w[1][l], c = s_f1w[2][l], d = s_f1w[3][l];
        float4 tot = make_float4(a.x+b.x+c.x+d.x, a.y+b.y+c.y+d.y,
                                 a.z+b.z+c.z+d.z, a.w+b.w+c.w+d.w);
        reinterpret_cast<float4*>(F1)[(size_t)m * 64 + l] = tot;
    }

    // --- phase B: gram, lower-triangle tiles only, float4 LDS reads ---
    const int tr = tid & 15, tcg = tid >> 4;
    const int i0 = tr * 4, j0 = tcg * 4;
    if (tcg <= tr) {
        float g[4][4];
#pragma unroll
        for (int r = 0; r < 4; ++r)
#pragma unroll
            for (int c = 0; c < 4; ++c) g[r][c] = 0.f;
        for (int k4 = 0; k4 < 64; ++k4) {
            float4 A0 = *reinterpret_cast<const float4*>(&sU[(i0    ) * SU_STRIDE + 4*k4]);
            float4 A1 = *reinterpret_cast<const float4*>(&sU[(i0 + 1) * SU_STRIDE + 4*k4]);
            float4 A2 = *reinterpret_cast<const float4*>(&sU[(i0 + 2) * SU_STRIDE + 4*k4]);
            float4 A3 = *reinterpret_cast<const float4*>(&sU[(i0 + 3) * SU_STRIDE + 4*k4]);
            float4 B0 = *reinterpret_cast<const float4*>(&sU[(j0    ) * SU_STRIDE + 4*k4]);
            float4 B1 = *reinterpret_cast<const float4*>(&sU[(j0 + 1) * SU_STRIDE + 4*k4]);
            float4 B2 = *reinterpret_cast<const float4*>(&sU[(j0 + 2) * SU_STRIDE + 4*k4]);
            float4 B3 = *reinterpret_cast<const float4*>(&sU[(j0 + 3) * SU_STRIDE + 4*k4]);
            g[0][0] += dot4v(A0, B0); g[0][1] += dot4v(A0, B1);
            g[0][2] += dot4v(A0, B2); g[0][3] += dot4v(A0, B3);
            g[1][0] += dot4v(A1, B0); g[1][1] += dot4v(A1, B1);
            g[1][2] += dot4v(A1, B2); g[1][3] += dot4v(A1, B3);
            g[2][0] += dot4v(A2, B0); g[2][1] += dot4v(A2, B1);
            g[2][2] += dot4v(A2, B2); g[2][3] += dot4v(A2, B3);
            g[3][0] += dot4v(A3, B0); g[3][1] += dot4v(A3, B1);
            g[3][2] += dot4v(A3, B2); g[3][3] += dot4v(A3, B3);
        }
#pragma unroll
        for (int r = 0; r < 4; ++r)
#pragma unroll
            for (int c = 0; c < 4; ++c) {
                int gi = i0 + r, gj = j0 + c;
                float val = 0.f;
                if (gj < gi) {
                    val = ALPHA * g[r][c];
                    if (type == 2) val *= s_pd[gi - gj];
                }
                sA[gi * 65 + gj] = val;
            }
    } else {
#pragma unroll
        for (int r = 0; r < 4; ++r)
#pragma unroll
            for (int c = 0; c < 4; ++c)
                sA[(i0 + r) * 65 + j0 + c] = 0.f;
    }
    __syncthreads();

    // --- bias (type 2): bias_i = (1/alpha) * sum_j A_ij sv_j ---
    if (type == 2 && wv == 0) {
        float dotb = 0.f;
#pragma unroll
        for (int jj = 0; jj < 64; ++jj)
            dotb = fmaf(sA[l * 65 + jj], s_sv[jj], dotb);
        biasF[m * 64 + l] = dotb * (1.0f / ALPHA);
    }

    // --- phase C: X = (I+A)^{-1}, wave-staged forward substitution (validated r6-r8) ---
    {
        const int base = wv * 16;
        float x[16];
#pragma unroll
        for (int r = 0; r < 16; ++r) x[r] = (base + r == l) ? 1.f : 0.f;
        for (int s = 0; s < 4; ++s) {
            if (wv == s) {
#pragma unroll
                for (int i = 1; i < 16; ++i)
#pragma unroll
                    for (int jj = 0; jj < 16; ++jj)
                        if (jj < i)
                            x[i] = fmaf(-sA[(base + i) * 65 + (base + jj)], x[jj], x[i]);
#pragma unroll
                for (int r = 0; r < 16; ++r) sX[(base + r) * 65 + l] = x[r];
            }
            __syncthreads();
            if (wv > s) {
#pragma unroll
                for (int i = 0; i < 16; ++i) {
                    float xi = sX[(s * 16 + i) * 65 + l];
#pragma unroll
                    for (int r = 0; r < 16; ++r)
                        x[r] = fmaf(-sA[(base + r) * 65 + (s * 16 + i)], xi, x[r]);
                }
            }
        }
    }
    __syncthreads();

    // --- store XT for all blocks (solve + accum consume it) ---
    float* dstA = AinvT + (size_t)bid * 4096;
    for (int idx = tid; idx < 4096; idx += 256) {
        int jcol = idx >> 6, irow = idx & 63;
        dstA[idx] = sX[irow * 65 + jcol];
    }
}

// ------------- Kernel 3: solver, 2 blocks x 512 threads, XT-based c = Xb -------------
__global__ __launch_bounds__(512) void solve_kernel(
    const float* __restrict__ USrev, const float* __restrict__ UPrev,
    const float* __restrict__ UPfwd, const float* __restrict__ AinvT,
    const float* __restrict__ F1, const float* __restrict__ biasF,
    const float* __restrict__ q,
    float* __restrict__ BS, float* __restrict__ BPB1, float* __restrict__ BPB2,
    float* __restrict__ gscal, int NCS, int NCP)
{
    __shared__ float s_cp[8][64], s_cp2[8][64];
    __shared__ float4 s_part[8][64], s_part2[8][64];
    __shared__ float s_powd[65];
    const int tid = threadIdx.x, wave = tid >> 6, l = tid & 63;
    const int wb = wave * 8;
    if (tid <= 64) s_powd[tid] = powf(P_DECAY, (float)tid);

    float4 q4 = reinterpret_cast<const float4*>(q)[l];
    float qs[1] = { dot4v(q4, q4) };
    wave_allred_arr(qs);
    float qinv = 1.0f / fmaxf(sqrtf(qs[0]), 1e-12f);
    float4 qn = make_float4(q4.x * qinv, q4.y * qinv, q4.z * qinv, q4.w * qinv);
    __syncthreads();

    if (blockIdx.x == 0) {
        // ============ sentence backward: NCS chunks ============
        float4 w1 = qn;
        const float4* U4 = reinterpret_cast<const float4*>(USrev);
        float4 curU[8]; float curX[8];
#pragma unroll
        for (int r = 0; r < 8; ++r) {
            curU[r] = U4[(size_t)(wb + r) * 64 + l];
            curX[r] = AinvT[(size_t)(wb + r) * 64 + l];
        }
        for (int m = 0; m < NCS; ++m) {
            float4 nxtU[8]; float nxtX[8];
            if (m + 1 < NCS) {
#pragma unroll
                for (int r = 0; r < 8; ++r) {
                    nxtU[r] = U4[(size_t)(m + 1) * 4096 + (size_t)(wb + r) * 64 + l];
                    nxtX[r] = AinvT[(size_t)(m + 1) * 4096 + (size_t)(wb + r) * 64 + l];
                }
            }
            float d[8];
#pragma unroll
            for (int r = 0; r < 8; ++r) d[r] = dot4v(curU[r], w1);
            wave_allred_arr(d);
            if (l == 0) {
#pragma unroll
                for (int r = 0; r < 8; ++r) BS[m * 64 + wb + r] = d[r];
            }
            float cp = 0.f;
#pragma unroll
            for (int r = 0; r < 8; ++r) cp = fmaf(curX[r], d[r], cp);
            s_cp[wave][l] = cp;
            __syncthreads();
            float cl = 0.f;
#pragma unroll
            for (int w = 0; w < 8; ++w) cl += s_cp[w][l];
            float4 part = make_float4(0.f, 0.f, 0.f, 0.f);
#pragma unroll
            for (int r = 0; r < 8; ++r) {
                float ci = rl(cl, wb + r);
                part.x = fmaf(ci, curU[r].x, part.x); part.y = fmaf(ci, curU[r].y, part.y);
                part.z = fmaf(ci, curU[r].z, part.z); part.w = fmaf(ci, curU[r].w, part.w);
            }
            s_part[wave][l] = part;
            __syncthreads();
            float4 s = make_float4(0.f, 0.f, 0.f, 0.f);
#pragma unroll
            for (int w = 0; w < 8; ++w) {
                float4 p = s_part[w][l];
                s.x += p.x; s.y += p.y; s.z += p.z; s.w += p.w;
            }
            w1.x = fmaf(-ALPHA, s.x, w1.x); w1.y = fmaf(-ALPHA, s.y, w1.y);
            w1.z = fmaf(-ALPHA, s.z, w1.z); w1.w = fmaf(-ALPHA, s.w, w1.w);
            if (m + 1 < NCS) {
#pragma unroll
                for (int r = 0; r < 8; ++r) { curU[r] = nxtU[r]; curX[r] = nxtX[r]; }
            }
        }
    } else {
        // ============ paragraph backward (dual RHS): NCP chunks ============
        {
            float4 w1 = qn;
            float4 w2 = make_float4(1.f, 1.f, 1.f, 1.f);
            const float4* U4 = reinterpret_cast<const float4*>(UPrev);
            float4 curU[8]; float curX[8];
#pragma unroll
            for (int r = 0; r < 8; ++r) {
                curU[r] = U4[(size_t)(wb + r) * 64 + l];
                curX[r] = AinvT[(size_t)NCS * 4096 + (size_t)(wb + r) * 64 + l];
            }
            for (int m = 0; m < NCP; ++m) {
                float4 nxtU[8]; float nxtX[8];
                if (m + 1 < NCP) {
#pragma unroll
                    for (int r = 0; r < 8; ++r) {
                        nxtU[r] = U4[(size_t)(m + 1) * 4096 + (size_t)(wb + r) * 64 + l];
                        nxtX[r] = AinvT[(size_t)(NCS + m + 1) * 4096 + (size_t)(wb + r) * 64 + l];
                    }
                }
                float d[16];
#pragma unroll
                for (int r = 0; r < 8; ++r) {
                    d[r]     = dot4v(curU[r], w1);
                    d[8 + r] = dot4v(curU[r], w2);
                }
                wave_allred_arr(d);
                if (l == 0) {
#pragma unroll
                    for (int r = 0; r < 8; ++r) {
                        BPB1[m * 64 + wb + r] = d[r];
                        BPB2[m * 64 + wb + r] = d[8 + r];
                    }
                }
                float cp1 = 0.f, cp2 = 0.f;
#pragma unroll
                for (int r = 0; r < 8; ++r) {
                    cp1 = fmaf(curX[r], d[r], cp1);
                    cp2 = fmaf(curX[r], d[8 + r], cp2);
                }
                s_cp[wave][l] = cp1; s_cp2[wave][l] = cp2;
                __syncthreads();
                float cl1 = 0.f, cl2 = 0.f;
#pragma unroll
                for (int w = 0; w < 8; ++w) { cl1 += s_cp[w][l]; cl2 += s_cp2[w][l]; }
                float4 p1 = make_float4(0.f,0.f,0.f,0.f), p2 = make_float4(0.f,0.f,0.f,0.f);
#pragma unroll
                for (int r = 0; r < 8; ++r) {
                    float c1 = rl(cl1, wb + r), c2 = rl(cl2, wb + r);
                    p1.x = fmaf(c1, curU[r].x, p1.x); p1.y = fmaf(c1, curU[r].y, p1.y);
                    p1.z = fmaf(c1, curU[r].z, p1.z); p1.w = fmaf(c1, curU[r].w, p1.w);
                    p2.x = fmaf(c2, curU[r].x, p2.x); p2.y = fmaf(c2, curU[r].y, p2.y);
                    p2.z = fmaf(c2, curU[r].z, p2.z); p2.w = fmaf(c2, curU[r].w, p2.w);
                }
                s_part[wave][l] = p1; s_part2[wave][l] = p2;
                __syncthreads();
                float4 s1 = make_float4(0.f,0.f,0.f,0.f), s2 = make_float4(0.f,0.f,0.f,0.f);
#pragma unroll
                for (int w = 0; w < 8; ++w) {
                    float4 a = s_part[w][l];  float4 b = s_part2[w][l];
                    s1.x += a.x; s1.y += a.y; s1.z += a.z; s1.w += a.w;
                    s2.x += b.x; s2.y += b.y; s2.z += b.z; s2.w += b.w;
                }
                w1.x = fmaf(-ALPHA, s1.x, w1.x); w1.y = fmaf(-ALPHA, s1.y, w1.y);
                w1.z = fmaf(-ALPHA, s1.z, w1.z); w1.w = fmaf(-ALPHA, s1.w, w1.w);
                w2.x = fmaf(-ALPHA, s2.x, w2.x); w2.y = fmaf(-ALPHA, s2.y, w2.y);
                w2.z = fmaf(-ALPHA, s2.z, w2.z); w2.w = fmaf(-ALPHA, s2.w, w2.w);
                if (m + 1 < NCP) {
#pragma unroll
                    for (int r = 0; r < 8; ++r) { curU[r] = nxtU[r]; curX[r] = nxtX[r]; }
                }
            }
        }
        __syncthreads();
        // ============ paragraph forward: NCP chunks ============
        float4 y = make_float4(0.f, 0.f, 0.f, 0.f);
        {
            const float4* U4 = reinterpret_cast<const float4*>(UPfwd);
            float4 curU[8]; float curX[8];
#pragma unroll
            for (int r = 0; r < 8; ++r) {
                curU[r] = U4[(size_t)(wb + r) * 64 + l];
                curX[r] = AinvT[(size_t)(NCS + NCP) * 4096 + (size_t)(wb + r) * 64 + l];
            }
            for (int m = 0; m < NCP; ++m) {
                float4 nxtU[8]; float nxtX[8];
                if (m + 1 < NCP) {
#pragma unroll
                    for (int r = 0; r < 8; ++r) {
                        nxtU[r] = U4[(size_t)(m + 1) * 4096 + (size_t)(wb + r) * 64 + l];
                        nxtX[r] = AinvT[(size_t)(NCS + NCP + m + 1) * 4096 + (size_t)(wb + r) * 64 + l];
                    }
                }
                float biasr[8];
#pragma unroll
                for (int r = 0; r < 8; ++r) biasr[r] = biasF[m * 64 + wb + r];
                float4 f1 = reinterpret_cast<const float4*>(F1)[(size_t)m * 64 + l];
                float d[8];
#pragma unroll
                for (int r = 0; r < 8; ++r) d[r] = dot4v(curU[r], y);
                wave_allred_arr(d);
#pragma unroll
                for (int r = 0; r < 8; ++r)
                    d[r] = fmaf(s_powd[wb + r + 1], d[r], biasr[r]);
                float cp = 0.f;
#pragma unroll
                for (int r = 0; r < 8; ++r) cp = fmaf(curX[r], d[r], cp);
                s_cp[wave][l] = cp;
                __syncthreads();
                float cl = 0.f;
#pragma unroll
                for (int w = 0; w < 8; ++w) cl += s_cp[w][l];
                float4 part = make_float4(0.f, 0.f, 0.f, 0.f);
#pragma unroll
                for (int r = 0; r < 8; ++r) {
                    float ci = s_powd[63 - (wb + r)] * rl(cl, wb + r);
                    part.x = fmaf(ci, curU[r].x, part.x); part.y = fmaf(ci, curU[r].y, part.y);
                    part.z = fmaf(ci, curU[r].z, part.z); part.w = fmaf(ci, curU[r].w, part.w);
                }
                s_part[wave][l] = part;
                __syncthreads();
                float4 s = make_float4(0.f, 0.f, 0.f, 0.f);
#pragma unroll
                for (int w = 0; w < 8; ++w) {
                    float4 p = s_part[w][l];
                    s.x += p.x; s.y += p.y; s.z += p.z; s.w += p.w;
                }
                float d64 = s_powd[64];
                y.x = fmaf(d64, y.x, fmaf(-ALPHA, s.x, f1.x));
                y.y = fmaf(d64, y.y, fmaf(-ALPHA, s.y, f1.y));
                y.z = fmaf(d64, y.z, fmaf(-ALPHA, s.z, f1.z));
                y.w = fmaf(d64, y.w, fmaf(-ALPHA, s.w, f1.w));
                if (m + 1 < NCP) {
#pragma unroll
                    for (int r = 0; r < 8; ++r) { curU[r] = nxtU[r]; curX[r] = nxtX[r]; }
                }
            }
        }
        float fin[2] = { dot4v(y, y), dot4v(qn, y) };
        wave_allred_arr(fin);
        if (tid == 0) gscal[0] = fin[1] / fmaxf(sqrtf(fin[0]), 2.56e-10f);
    }
}

// ------------- Kernel 4: c = X b, then weighted accumulation -> atomic combine -------------
__global__ __launch_bounds__(256) void accum_kernel(
    const float* __restrict__ V, const float* __restrict__ PV,
    const float* __restrict__ AinvT,
    const float* __restrict__ BS, const float* __restrict__ BPB1,
    const float* __restrict__ BPB2, const float* __restrict__ gscal,
    float* __restrict__ out, int T, int P, int NCS, int NCP)
{
    __shared__ float s_b[64], s_cp[4][64], wc[64];
    const int b = blockIdx.x, t = threadIdx.x;
    const float* src; const float* B; int i0, realN, chunk, ci; float decay;
    if (b < NCS)            { src = V;  B = BS;   ci = b;             realN = T; decay = S_DECAY; chunk = b; }
    else if (b < NCS + NCP) { src = PV; B = BPB1; ci = b - NCS;       realN = P; decay = P_DECAY; chunk = b; }
    else                    { src = PV; B = BPB2; ci = b - NCS - NCP; realN = P; decay = P_DECAY; chunk = b - NCP; }
    i0 = ci * 64;
    if (t < 64) s_b[t] = B[ci * 64 + t];
    __syncthreads();
    {
        const int part = t >> 6, k = t & 63;
        const float* Xc = AinvT + (size_t)chunk * 4096;
        float cp = 0.f;
#pragma unroll
        for (int jj = 0; jj < 16; ++jj) {
            int j = part * 16 + jj;
            cp = fmaf(Xc[j * 64 + k], s_b[j], cp);
        }
        s_cp[part][k] = cp;
    }
    __syncthreads();
    if (t < 64) {
        float c = s_cp[0][t] + s_cp[1][t] + s_cp[2][t] + s_cp[3][t];
        wc[t] = powf(decay, (float)(i0 + t)) * c;
    }
    __syncthreads();
    const int k = t;
    float acc = 0.f;
    for (int ii = 0; ii < 64; ++ii) {
        int i = i0 + ii;
        if (i < realN)
            acc = fmaf(wc[ii], src[(size_t)(realN - 1 - i) * DK + k], acc);
    }
    float wlev;
    if (b < NCS)            wlev = 0.2f;
    else if (b < NCS + NCP) wlev = 0.3f;
    else                    wlev = (0.5f / 256.0f) * gscal[0];
    atomicAdd(&out[k], wlev * acc);
}

extern "C" void kernel_launch(void* const* d_in, const int* in_sizes, int n_in,
                              void* d_out, int out_size, void* d_ws, size_t ws_size,
                              hipStream_t stream) {
    const float* emb = (const float*)d_in[0];
    const float* q   = (const float*)d_in[1];
    const float* Wk  = (const float*)d_in[2];
    const float* bk  = (const float*)d_in[3];
    const float* Wv  = (const float*)d_in[4];
    const float* bv  = (const float*)d_in[5];

    const int T = in_sizes[0] / D_EMB;        // 1000
    const int P = T / 5;                      // 200
    const int NCS  = (T + 63) / 64;           // 16
    const int NCP  = (P + 63) / 64;           // 4
    const int PADS = NCS * 64;                // 1024
    const int PADP = NCP * 64;                // 256
    const int NCH  = NCS + 2 * NCP;           // 24

    float* ws    = (float*)d_ws;
    float* K     = ws;                               // T*256
    float* V     = K     + (size_t)T * DK;           // T*256
    float* PV    = V     + (size_t)T * DK;           // PADP*256
    float* USrev = PV    + (size_t)PADP * DK;        // PADS*256
    float* UPrev = USrev + (size_t)PADS * DK;        // PADP*256
    float* UPfwd = UPrev + (size_t)PADP * DK;        // PADP*256
    float* SVv   = UPfwd + (size_t)PADP * DK;        // PADP
    float* AinvT = SVv   + PADP;                     // NCH*4096
    float* F1    = AinvT + (size_t)NCH * 4096;       // NCP*256
    float* biasF = F1    + (size_t)NCP * 256;        // PADP
    float* BS    = biasF + PADP;                     // PADS
    float* BPB1  = BS    + PADS;                     // PADP
    float* BPB2  = BPB1  + PADP;                     // PADP
    float* gscal = BPB2  + PADP;                     // 4

    prep_kernel<<<(T / 4) * 2 + 1, 256, 0, stream>>>(emb, Wk, bk, Wv, bv,
                                                     K, V, USrev, (float*)d_out, T);
    graminv_kernel<<<NCH, 256, 0, stream>>>(K, V, USrev, UPrev, UPfwd,
                                            PV, SVv, AinvT, F1, biasF, P, NCS, NCP);
    solve_kernel<<<2, 512, 0, stream>>>(USrev, UPrev, UPfwd, AinvT, F1, biasF, q,
                                        BS, BPB1, BPB2, gscal, NCS, NCP);
    accum_kernel<<<NCH, 256, 0, stream>>>(V, PV, AinvT, BS, BPB1, BPB2, gscal,
                                          (float*)d_out, T, P, NCS, NCP);
}